// Round 3
// baseline (132.708 us; speedup 1.0000x reference)
//
#include <hip/hip_runtime.h>
#include <stdint.h>

#define NPTS 2097152
#define BLOCK 256
#define PPT 8
#define NBLK (NPTS / (BLOCK * PPT))   // 1024 blocks

static __device__ __forceinline__ float silu_f(float v) {
    return v * __builtin_amdgcn_rcpf(1.0f + __expf(-v));
}

__global__ __launch_bounds__(BLOCK) void camfield_kernel(
    const float* __restrict__ xy,
    const float* __restrict__ gamma,
    const float* __restrict__ beta,
    const float* __restrict__ w_in,
    const float* __restrict__ b_in,
    const float* __restrict__ w_h,
    const float* __restrict__ b_h,
    const float* __restrict__ w_out,
    const float* __restrict__ b_out,
    const float* __restrict__ ln_w,
    const float* __restrict__ ln_b,
    float* __restrict__ out)
{
    // LDS grid cache: [layer][cell=y*16+x][ch] ch: 0..5 gamma, 6..11 beta
    // cell stride = 48 B = 3x16B -> every cell base is 16B-aligned (ds_read_b128)
    __shared__ float sg[2][256][12];

    const int tid = threadIdx.x;

    // ---- stage grids (fp32 global -> fp32 LDS), 6144 elems / 256 thr = 24 iters
    for (int idx = tid; idx < 6144; idx += BLOCK) {
        int lc = idx >> 8;          // 0..23 = l*12 + c
        int cell = idx & 255;
        int l = lc / 12;
        int c = lc - l * 12;
        float v;
        if (c < 6) v = gamma[l * 1536 + c * 256 + cell];
        else       v = beta [l * 1536 + (c - 6) * 256 + cell];
        sg[l][cell][c] = v;
    }

    // ---- weights to registers (wave-uniform; compiler should scalarize)
    float Win0[6], Win1[6], Bin[6], Wh[6][6], Bh[6], Wo[3][6], Bo[3], LnW[2][6], LnB[2][6];
#pragma unroll
    for (int j = 0; j < 6; ++j) {
        Win0[j] = w_in[2 * j];
        Win1[j] = w_in[2 * j + 1];
        Bin[j]  = b_in[j];
        Bh[j]   = b_h[j];
#pragma unroll
        for (int k = 0; k < 6; ++k) Wh[j][k] = w_h[6 * j + k];
        LnW[0][j] = ln_w[j];     LnW[1][j] = ln_w[6 + j];
        LnB[0][j] = ln_b[j];     LnB[1][j] = ln_b[6 + j];
    }
#pragma unroll
    for (int j = 0; j < 3; ++j) {
        Bo[j] = b_out[j];
#pragma unroll
        for (int k = 0; k < 6; ++k) Wo[j][k] = w_out[6 * j + k];
    }

    __syncthreads();

    const int p0 = (blockIdx.x * BLOCK + tid) * PPT;

    // 8 points * 2 fp32 = 64 B, 16B-aligned
    const float4* xv = (const float4*)(xy + 2 * p0);
    float4 q0 = xv[0];
    float4 q1 = xv[1];
    float4 q2 = xv[2];
    float4 q3 = xv[3];
    float xs[8] = { q0.x, q0.z, q1.x, q1.z, q2.x, q2.z, q3.x, q3.z };
    float ys[8] = { q0.y, q0.w, q1.y, q1.w, q2.y, q2.w, q3.y, q3.w };

    float o[3 * PPT];

#pragma unroll
    for (int p = 0; p < PPT; ++p) {
        const float x = xs[p];
        const float y = ys[p];

        // coords: clip((xy+1)*0.5*15, 0, 15); clamp x0<=14 so x1=x0+1 always valid
        float fx = fminf(fmaxf(fmaf(x, 7.5f, 7.5f), 0.0f), 15.0f);
        float fy = fminf(fmaxf(fmaf(y, 7.5f, 7.5f), 0.0f), 15.0f);
        int x0 = (int)fx; if (x0 > 14) x0 = 14;
        int y0 = (int)fy; if (y0 > 14) y0 = 14;
        float wx = fx - (float)x0;
        float wy = fy - (float)y0;
        float w11 = wx * wy;
        float w10 = wy - w11;              // (1-wx)*wy
        float w01 = wx - w11;              // wx*(1-wy)
        float w00 = 1.0f - wx - wy + w11;  // (1-wx)*(1-wy)

        const int cell = (y0 << 4) + x0;

        float gl[2][6], bl[2][6];
#pragma unroll
        for (int l = 0; l < 2; ++l) {
            const float* base = &sg[l][cell][0];
            float v[12];
#pragma unroll
            for (int q = 0; q < 3; ++q) {
                float4 A = *(const float4*)(base + 4 * q);          // (y0,x0)
                float4 B = *(const float4*)(base + 12 + 4 * q);     // (y0,x0+1)
                float4 C = *(const float4*)(base + 192 + 4 * q);    // (y0+1,x0)
                float4 D = *(const float4*)(base + 204 + 4 * q);    // (y0+1,x0+1)
                v[4 * q + 0] = fmaf(A.x, w00, fmaf(B.x, w01, fmaf(C.x, w10, D.x * w11)));
                v[4 * q + 1] = fmaf(A.y, w00, fmaf(B.y, w01, fmaf(C.y, w10, D.y * w11)));
                v[4 * q + 2] = fmaf(A.z, w00, fmaf(B.z, w01, fmaf(C.z, w10, D.z * w11)));
                v[4 * q + 3] = fmaf(A.w, w00, fmaf(B.w, w01, fmaf(C.w, w10, D.w * w11)));
            }
#pragma unroll
            for (int c = 0; c < 6; ++c) { gl[l][c] = v[c]; bl[l][c] = v[6 + c]; }
        }

        // input layer: h = silu(x*Win0 + y*Win1 + Bin)
        float h[6];
#pragma unroll
        for (int j = 0; j < 6; ++j)
            h[j] = silu_f(fmaf(x, Win0[j], fmaf(y, Win1[j], Bin[j])));

        // layer 0: h = g * LN(h) + b
        {
            float mu = (h[0] + h[1] + h[2] + h[3] + h[4] + h[5]) * (1.0f / 6.0f);
            float d[6], var = 0.0f;
#pragma unroll
            for (int j = 0; j < 6; ++j) { d[j] = h[j] - mu; var = fmaf(d[j], d[j], var); }
            var *= (1.0f / 6.0f);
            float rs = __builtin_amdgcn_rsqf(var + 1e-5f);
#pragma unroll
            for (int j = 0; j < 6; ++j)
                h[j] = fmaf(gl[0][j], fmaf(d[j] * rs, LnW[0][j], LnB[0][j]), bl[0][j]);
        }

        // hidden layer: t = silu(h @ Wh^T + Bh)
        float t[6];
#pragma unroll
        for (int j = 0; j < 6; ++j) {
            float a = Bh[j];
#pragma unroll
            for (int k = 0; k < 6; ++k) a = fmaf(h[k], Wh[j][k], a);
            t[j] = silu_f(a);
        }

        // layer 1: t = g * LN(t) + b
        {
            float mu = (t[0] + t[1] + t[2] + t[3] + t[4] + t[5]) * (1.0f / 6.0f);
            float d[6], var = 0.0f;
#pragma unroll
            for (int j = 0; j < 6; ++j) { d[j] = t[j] - mu; var = fmaf(d[j], d[j], var); }
            var *= (1.0f / 6.0f);
            float rs = __builtin_amdgcn_rsqf(var + 1e-5f);
#pragma unroll
            for (int j = 0; j < 6; ++j)
                t[j] = fmaf(gl[1][j], fmaf(d[j] * rs, LnW[1][j], LnB[1][j]), bl[1][j]);
        }

        // output layer
#pragma unroll
        for (int j = 0; j < 3; ++j) {
            float a = Bo[j];
#pragma unroll
            for (int k = 0; k < 6; ++k) a = fmaf(t[k], Wo[j][k], a);
            o[3 * p + j] = a;
        }
    }

    // store 24 fp32 = 96 B per thread, 16B-aligned (3*p0 = 24*global_tid)
    float4* op = (float4*)(out + 3 * p0);
#pragma unroll
    for (int q = 0; q < 6; ++q)
        op[q] = make_float4(o[4 * q], o[4 * q + 1], o[4 * q + 2], o[4 * q + 3]);
}

extern "C" void kernel_launch(void* const* d_in, const int* in_sizes, int n_in,
                              void* d_out, int out_size, void* d_ws, size_t ws_size,
                              hipStream_t stream) {
    camfield_kernel<<<NBLK, BLOCK, 0, stream>>>(
        (const float*)d_in[0],  // xy
        (const float*)d_in[1],  // gamma
        (const float*)d_in[2],  // beta
        (const float*)d_in[3],  // w_in
        (const float*)d_in[4],  // b_in
        (const float*)d_in[5],  // w_h
        (const float*)d_in[6],  // b_h
        (const float*)d_in[7],  // w_out
        (const float*)d_in[8],  // b_out
        (const float*)d_in[9],  // ln_w
        (const float*)d_in[10], // ln_b
        (float*)d_out);
}

// Round 5
// 115.102 us; speedup vs baseline: 1.1530x; 1.1530x over previous
//
#include <hip/hip_runtime.h>
#include <hip/hip_fp16.h>
#include <stdint.h>

#define NPTS 2097152
#define BLOCK 256
#define PPT 4
#define NBLK (NPTS / (BLOCK * PPT))   // 2048 blocks

static __device__ __forceinline__ float silu_f(float v) {
    return v * __builtin_amdgcn_rcpf(1.0f + __expf(-v));
}
static __device__ __forceinline__ __half2 u2h(uint32_t u) {
    union { uint32_t i; __half2 h; } v; v.i = u; return v.h;
}

__global__ __launch_bounds__(BLOCK, 4) void camfield_kernel(
    const float* __restrict__ xy,
    const float* __restrict__ gamma,
    const float* __restrict__ beta,
    const float* __restrict__ w_in,
    const float* __restrict__ b_in,
    const float* __restrict__ w_h,
    const float* __restrict__ b_h,
    const float* __restrict__ w_out,
    const float* __restrict__ b_out,
    const float* __restrict__ ln_w,
    const float* __restrict__ ln_b,
    float* __restrict__ out)
{
    // LDS: [layer][cell=y*16+x][6 half2 pairs] = 24 B/cell, 12 KB total.
    // pairs 0..2 = gamma ch {2c,2c+1}, pairs 3..5 = beta ch {2(c-3),2(c-3)+1}
    __shared__ uint32_t sg[2][256][6];

    const int tid = threadIdx.x;

    // ---- stage grids: fp32 global -> packed half2 LDS. 3072 pairs.
    // layer stride is 1536 (NOT pow2) — decompose by compare, not mask.
    for (int idx = tid; idx < 3072; idx += BLOCK) {
        int l = (idx >= 1536) ? 1 : 0;
        int r = idx - l * 1536;            // 0..1535
        int c = r >> 8;                    // pair 0..5
        int cell = r & 255;
        const float* src = (c < 3) ? (gamma + l * 1536 + (2 * c) * 256 + cell)
                                   : (beta  + l * 1536 + (2 * (c - 3)) * 256 + cell);
        float lo = src[0];
        float hi = src[256];
        __half2 h = __floats2half2_rn(lo, hi);
        union { __half2 h; uint32_t i; } pk; pk.h = h;
        sg[l][cell][c] = pk.i;
    }

    // ---- weights to registers (wave-uniform; scalarized)
    float Win0[6], Win1[6], Bin[6], Wh[6][6], Bh[6], Wo[3][6], Bo[3], LnW[2][6], LnB[2][6];
#pragma unroll
    for (int j = 0; j < 6; ++j) {
        Win0[j] = w_in[2 * j];
        Win1[j] = w_in[2 * j + 1];
        Bin[j]  = b_in[j];
        Bh[j]   = b_h[j];
#pragma unroll
        for (int k = 0; k < 6; ++k) Wh[j][k] = w_h[6 * j + k];
        LnW[0][j] = ln_w[j];     LnW[1][j] = ln_w[6 + j];
        LnB[0][j] = ln_b[j];     LnB[1][j] = ln_b[6 + j];
    }
#pragma unroll
    for (int j = 0; j < 3; ++j) {
        Bo[j] = b_out[j];
#pragma unroll
        for (int k = 0; k < 6; ++k) Wo[j][k] = w_out[6 * j + k];
    }

    __syncthreads();

    const int p0 = (blockIdx.x * BLOCK + tid) * PPT;

    // 4 points * 2 fp32 = 32 B, 16B-aligned
    const float4* xv = (const float4*)(xy + 2 * p0);
    float4 q0 = xv[0];
    float4 q1 = xv[1];
    float xs[4] = { q0.x, q0.z, q1.x, q1.z };
    float ys[4] = { q0.y, q0.w, q1.y, q1.w };

    float o[3 * PPT];

#pragma unroll
    for (int p = 0; p < PPT; ++p) {
        const float x = xs[p];
        const float y = ys[p];

        float fx = fminf(fmaxf(fmaf(x, 7.5f, 7.5f), 0.0f), 15.0f);
        float fy = fminf(fmaxf(fmaf(y, 7.5f, 7.5f), 0.0f), 15.0f);
        int x0 = (int)fx; if (x0 > 14) x0 = 14;
        int y0 = (int)fy; if (y0 > 14) y0 = 14;
        float wx = fx - (float)x0;
        float wy = fy - (float)y0;
        float w11f = wx * wy;
        float w10f = wy - w11f;
        float w01f = wx - w11f;
        float w00f = 1.0f - wx - wy + w11f;

        const __half2 W00 = __float2half2_rn(w00f);
        const __half2 W01 = __float2half2_rn(w01f);
        const __half2 W10 = __float2half2_rn(w10f);
        const __half2 W11 = __float2half2_rn(w11f);

        const int cell = (y0 << 4) + x0;

        float gl[2][6], bl[2][6];
#pragma unroll
        for (int l = 0; l < 2; ++l) {
            const uint32_t* base = &sg[l][cell][0];
            // corners: A=+0 (y0,x0), B=+6 (x0+1), C=+96 (y0+1), D=+102 dwords
            uint2 a0 = *(const uint2*)(base + 0);
            uint2 a1 = *(const uint2*)(base + 2);
            uint2 a2 = *(const uint2*)(base + 4);
            uint2 b0 = *(const uint2*)(base + 6);
            uint2 b1 = *(const uint2*)(base + 8);
            uint2 b2 = *(const uint2*)(base + 10);
            uint2 c0 = *(const uint2*)(base + 96);
            uint2 c1 = *(const uint2*)(base + 98);
            uint2 c2 = *(const uint2*)(base + 100);
            uint2 d0 = *(const uint2*)(base + 102);
            uint2 d1 = *(const uint2*)(base + 104);
            uint2 d2 = *(const uint2*)(base + 106);

            float2 r[6];
            {
                uint32_t ua[6] = { a0.x, a0.y, a1.x, a1.y, a2.x, a2.y };
                uint32_t ub[6] = { b0.x, b0.y, b1.x, b1.y, b2.x, b2.y };
                uint32_t uc[6] = { c0.x, c0.y, c1.x, c1.y, c2.x, c2.y };
                uint32_t ud[6] = { d0.x, d0.y, d1.x, d1.y, d2.x, d2.y };
#pragma unroll
                for (int s = 0; s < 6; ++s) {
                    __half2 acc = __hmul2(u2h(ua[s]), W00);
                    acc = __hfma2(u2h(ub[s]), W01, acc);
                    acc = __hfma2(u2h(uc[s]), W10, acc);
                    acc = __hfma2(u2h(ud[s]), W11, acc);
                    r[s] = __half22float2(acc);
                }
            }
            gl[l][0] = r[0].x; gl[l][1] = r[0].y;
            gl[l][2] = r[1].x; gl[l][3] = r[1].y;
            gl[l][4] = r[2].x; gl[l][5] = r[2].y;
            bl[l][0] = r[3].x; bl[l][1] = r[3].y;
            bl[l][2] = r[4].x; bl[l][3] = r[4].y;
            bl[l][4] = r[5].x; bl[l][5] = r[5].y;
        }

        // input layer: h = silu(x*Win0 + y*Win1 + Bin)
        float h[6];
#pragma unroll
        for (int j = 0; j < 6; ++j)
            h[j] = silu_f(fmaf(x, Win0[j], fmaf(y, Win1[j], Bin[j])));

        // layer 0: h = g * LN(h) + b
        {
            float mu = (h[0] + h[1] + h[2] + h[3] + h[4] + h[5]) * (1.0f / 6.0f);
            float d[6], var = 0.0f;
#pragma unroll
            for (int j = 0; j < 6; ++j) { d[j] = h[j] - mu; var = fmaf(d[j], d[j], var); }
            var *= (1.0f / 6.0f);
            float rs = __builtin_amdgcn_rsqf(var + 1e-5f);
#pragma unroll
            for (int j = 0; j < 6; ++j)
                h[j] = fmaf(gl[0][j], fmaf(d[j] * rs, LnW[0][j], LnB[0][j]), bl[0][j]);
        }

        // hidden layer: t = silu(h @ Wh^T + Bh)
        float t[6];
#pragma unroll
        for (int j = 0; j < 6; ++j) {
            float a = Bh[j];
#pragma unroll
            for (int k = 0; k < 6; ++k) a = fmaf(h[k], Wh[j][k], a);
            t[j] = silu_f(a);
        }

        // layer 1: t = g * LN(t) + b
        {
            float mu = (t[0] + t[1] + t[2] + t[3] + t[4] + t[5]) * (1.0f / 6.0f);
            float d[6], var = 0.0f;
#pragma unroll
            for (int j = 0; j < 6; ++j) { d[j] = t[j] - mu; var = fmaf(d[j], d[j], var); }
            var *= (1.0f / 6.0f);
            float rs = __builtin_amdgcn_rsqf(var + 1e-5f);
#pragma unroll
            for (int j = 0; j < 6; ++j)
                t[j] = fmaf(gl[1][j], fmaf(d[j] * rs, LnW[1][j], LnB[1][j]), bl[1][j]);
        }

        // output layer
#pragma unroll
        for (int j = 0; j < 3; ++j) {
            float a = Bo[j];
#pragma unroll
            for (int k = 0; k < 6; ++k) a = fmaf(t[k], Wo[j][k], a);
            o[3 * p + j] = a;
        }
    }

    // store 12 fp32 = 48 B per thread, 16B-aligned
    float4* op = (float4*)(out + 3 * p0);
#pragma unroll
    for (int q = 0; q < 3; ++q)
        op[q] = make_float4(o[4 * q], o[4 * q + 1], o[4 * q + 2], o[4 * q + 3]);
}

extern "C" void kernel_launch(void* const* d_in, const int* in_sizes, int n_in,
                              void* d_out, int out_size, void* d_ws, size_t ws_size,
                              hipStream_t stream) {
    camfield_kernel<<<NBLK, BLOCK, 0, stream>>>(
        (const float*)d_in[0],  // xy
        (const float*)d_in[1],  // gamma
        (const float*)d_in[2],  // beta
        (const float*)d_in[3],  // w_in
        (const float*)d_in[4],  // b_in
        (const float*)d_in[5],  // w_h
        (const float*)d_in[6],  // b_h
        (const float*)d_in[7],  // w_out
        (const float*)d_in[8],  // b_out
        (const float*)d_in[9],  // ln_w
        (const float*)d_in[10], // ln_b
        (float*)d_out);
}

// Round 6
// 109.690 us; speedup vs baseline: 1.2098x; 1.0493x over previous
//
#include <hip/hip_runtime.h>
#include <hip/hip_fp16.h>
#include <stdint.h>

#define NPTS 2097152
#define BLOCK 256
#define PPT 4
#define NBLK (NPTS / (BLOCK * PPT))   // 2048 blocks

static __device__ __forceinline__ float silu_f(float v) {
    return v * __builtin_amdgcn_rcpf(1.0f + __expf(-v));
}
static __device__ __forceinline__ __half2 u2h(uint32_t u) {
    union { uint32_t i; __half2 h; } v; v.i = u; return v.h;
}
static __device__ __forceinline__ uint32_t h2u(__half2 h) {
    union { __half2 h; uint32_t i; } v; v.h = h; return v.i;
}

__global__ __launch_bounds__(BLOCK, 4) void camfield_kernel(
    const float* __restrict__ xy,
    const float* __restrict__ gamma,
    const float* __restrict__ beta,
    const float* __restrict__ w_in,
    const float* __restrict__ b_in,
    const float* __restrict__ w_h,
    const float* __restrict__ b_h,
    const float* __restrict__ w_out,
    const float* __restrict__ b_out,
    const float* __restrict__ ln_w,
    const float* __restrict__ ln_b,
    float* __restrict__ out)
{
    // LDS: x-duplicated cell lines. Per cell (y,x): 6 channel-pairs s, each
    // stored as [A_s = half2(ch at x), B_s = half2(ch at x+1 clamped)].
    // dword layout per cell: {A0,B0,A1,B1,A2,B2,A3,B3,A4,B4,A5,B5} = 48 B.
    // One bilinear patch = 3x b128 at cell + 3x b128 at cell+16 (row y0+1),
    // all immediate offsets from ONE base address. 2*256*48 B = 24 KB.
    __shared__ __align__(16) uint32_t sg[2][256][12];

    const int tid = threadIdx.x;

    // ---- stage grids: fp32 global -> packed half2 LDS. 3072 (l,s,cell) items.
    // layer stride 1536 is NOT pow2 — decompose by compare.
    for (int idx = tid; idx < 3072; idx += BLOCK) {
        int l = (idx >= 1536) ? 1 : 0;
        int r = idx - l * 1536;            // 0..1535
        int s = r >> 8;                    // pair 0..5
        int cell = r & 255;
        int x = cell & 15;
        int x1 = (x < 15) ? x + 1 : 15;    // border clamp baked into B
        int rowb = cell - x;               // y*16
        const float* src = (s < 3) ? (gamma + l * 1536 + (2 * s) * 256)
                                   : (beta  + l * 1536 + (2 * (s - 3)) * 256);
        float a_lo = src[rowb + x];
        float a_hi = src[256 + rowb + x];
        float b_lo = src[rowb + x1];
        float b_hi = src[256 + rowb + x1];
        sg[l][cell][2 * s]     = h2u(__floats2half2_rn(a_lo, a_hi));
        sg[l][cell][2 * s + 1] = h2u(__floats2half2_rn(b_lo, b_hi));
    }

    // ---- weights to registers (wave-uniform; scalarized)
    float Win0[6], Win1[6], Bin[6], Wh[6][6], Bh[6], Wo[3][6], Bo[3], LnW[2][6], LnB[2][6];
#pragma unroll
    for (int j = 0; j < 6; ++j) {
        Win0[j] = w_in[2 * j];
        Win1[j] = w_in[2 * j + 1];
        Bin[j]  = b_in[j];
        Bh[j]   = b_h[j];
#pragma unroll
        for (int k = 0; k < 6; ++k) Wh[j][k] = w_h[6 * j + k];
        LnW[0][j] = ln_w[j];     LnW[1][j] = ln_w[6 + j];
        LnB[0][j] = ln_b[j];     LnB[1][j] = ln_b[6 + j];
    }
#pragma unroll
    for (int j = 0; j < 3; ++j) {
        Bo[j] = b_out[j];
#pragma unroll
        for (int k = 0; k < 6; ++k) Wo[j][k] = w_out[6 * j + k];
    }

    __syncthreads();

    const int p0 = (blockIdx.x * BLOCK + tid) * PPT;

    // 4 points * 2 fp32 = 32 B, 16B-aligned
    const float4* xv = (const float4*)(xy + 2 * p0);
    float4 q0 = xv[0];
    float4 q1 = xv[1];
    float xs[4] = { q0.x, q0.z, q1.x, q1.z };
    float ys[4] = { q0.y, q0.w, q1.y, q1.w };

    float o[3 * PPT];

#pragma unroll
    for (int p = 0; p < PPT; ++p) {
        const float x = xs[p];
        const float y = ys[p];

        float fx = fminf(fmaxf(fmaf(x, 7.5f, 7.5f), 0.0f), 15.0f);
        float fy = fminf(fmaxf(fmaf(y, 7.5f, 7.5f), 0.0f), 15.0f);
        int x0 = (int)fx; if (x0 > 14) x0 = 14;
        int y0 = (int)fy; if (y0 > 14) y0 = 14;
        float wx = fx - (float)x0;
        float wy = fy - (float)y0;
        float w11f = wx * wy;
        float w10f = wy - w11f;
        float w01f = wx - w11f;
        float w00f = 1.0f - wx - wy + w11f;

        const __half2 W00 = __float2half2_rn(w00f);
        const __half2 W01 = __float2half2_rn(w01f);
        const __half2 W10 = __float2half2_rn(w10f);
        const __half2 W11 = __float2half2_rn(w11f);

        const int cell = (y0 << 4) + x0;

        float gl[2][6], bl[2][6];
#pragma unroll
        for (int l = 0; l < 2; ++l) {
            const uint4* c4 = (const uint4*)&sg[l][cell][0];
            // row y0: 3x b128; row y0+1: +16 cells = +48 uint4 (imm offset 768B)
            uint4 u0 = c4[0];
            uint4 u1 = c4[1];
            uint4 u2 = c4[2];
            uint4 v0 = c4[48];
            uint4 v1 = c4[49];
            uint4 v2 = c4[50];

            uint32_t A[6] = { u0.x, u0.z, u1.x, u1.z, u2.x, u2.z };
            uint32_t B[6] = { u0.y, u0.w, u1.y, u1.w, u2.y, u2.w };
            uint32_t C[6] = { v0.x, v0.z, v1.x, v1.z, v2.x, v2.z };
            uint32_t D[6] = { v0.y, v0.w, v1.y, v1.w, v2.y, v2.w };

            float2 r[6];
#pragma unroll
            for (int s = 0; s < 6; ++s) {
                __half2 acc = __hmul2(u2h(A[s]), W00);
                acc = __hfma2(u2h(B[s]), W01, acc);
                acc = __hfma2(u2h(C[s]), W10, acc);
                acc = __hfma2(u2h(D[s]), W11, acc);
                r[s] = __half22float2(acc);
            }
            gl[l][0] = r[0].x; gl[l][1] = r[0].y;
            gl[l][2] = r[1].x; gl[l][3] = r[1].y;
            gl[l][4] = r[2].x; gl[l][5] = r[2].y;
            bl[l][0] = r[3].x; bl[l][1] = r[3].y;
            bl[l][2] = r[4].x; bl[l][3] = r[4].y;
            bl[l][4] = r[5].x; bl[l][5] = r[5].y;
        }

        // input layer: h = silu(x*Win0 + y*Win1 + Bin)
        float h[6];
#pragma unroll
        for (int j = 0; j < 6; ++j)
            h[j] = silu_f(fmaf(x, Win0[j], fmaf(y, Win1[j], Bin[j])));

        // layer 0: h = g * LN(h) + b
        {
            float mu = (h[0] + h[1] + h[2] + h[3] + h[4] + h[5]) * (1.0f / 6.0f);
            float d[6], var = 0.0f;
#pragma unroll
            for (int j = 0; j < 6; ++j) { d[j] = h[j] - mu; var = fmaf(d[j], d[j], var); }
            var *= (1.0f / 6.0f);
            float rs = __builtin_amdgcn_rsqf(var + 1e-5f);
#pragma unroll
            for (int j = 0; j < 6; ++j)
                h[j] = fmaf(gl[0][j], fmaf(d[j] * rs, LnW[0][j], LnB[0][j]), bl[0][j]);
        }

        // hidden layer: t = silu(h @ Wh^T + Bh)
        float t[6];
#pragma unroll
        for (int j = 0; j < 6; ++j) {
            float a = Bh[j];
#pragma unroll
            for (int k = 0; k < 6; ++k) a = fmaf(h[k], Wh[j][k], a);
            t[j] = silu_f(a);
        }

        // layer 1: t = g * LN(t) + b
        {
            float mu = (t[0] + t[1] + t[2] + t[3] + t[4] + t[5]) * (1.0f / 6.0f);
            float d[6], var = 0.0f;
#pragma unroll
            for (int j = 0; j < 6; ++j) { d[j] = t[j] - mu; var = fmaf(d[j], d[j], var); }
            var *= (1.0f / 6.0f);
            float rs = __builtin_amdgcn_rsqf(var + 1e-5f);
#pragma unroll
            for (int j = 0; j < 6; ++j)
                t[j] = fmaf(gl[1][j], fmaf(d[j] * rs, LnW[1][j], LnB[1][j]), bl[1][j]);
        }

        // output layer
#pragma unroll
        for (int j = 0; j < 3; ++j) {
            float a = Bo[j];
#pragma unroll
            for (int k = 0; k < 6; ++k) a = fmaf(t[k], Wo[j][k], a);
            o[3 * p + j] = a;
        }
    }

    // store 12 fp32 = 48 B per thread, 16B-aligned
    float4* op = (float4*)(out + 3 * p0);
#pragma unroll
    for (int q = 0; q < 3; ++q)
        op[q] = make_float4(o[4 * q], o[4 * q + 1], o[4 * q + 2], o[4 * q + 3]);
}

extern "C" void kernel_launch(void* const* d_in, const int* in_sizes, int n_in,
                              void* d_out, int out_size, void* d_ws, size_t ws_size,
                              hipStream_t stream) {
    camfield_kernel<<<NBLK, BLOCK, 0, stream>>>(
        (const float*)d_in[0],  // xy
        (const float*)d_in[1],  // gamma
        (const float*)d_in[2],  // beta
        (const float*)d_in[3],  // w_in
        (const float*)d_in[4],  // b_in
        (const float*)d_in[5],  // w_h
        (const float*)d_in[6],  // b_h
        (const float*)d_in[7],  // w_out
        (const float*)d_in[8],  // b_out
        (const float*)d_in[9],  // ln_w
        (const float*)d_in[10], // ln_b
        (float*)d_out);
}